// Round 2
// baseline (12790.964 us; speedup 1.0000x reference)
//
#include <hip/hip_runtime.h>

#define CINCH 512
#define ICH 256
#define NP 4096
#define BB 4

typedef __attribute__((ext_vector_type(8))) short bf16x8;
typedef __attribute__((ext_vector_type(8))) unsigned short u16x8;
typedef __attribute__((ext_vector_type(4))) float f32x4;
typedef unsigned short u16;

__device__ __forceinline__ u16 f2bf(float f){
  unsigned u = __builtin_bit_cast(unsigned, f);
  u += 0x7FFFu + ((u>>16)&1u);
  return (u16)(u>>16);
}

__device__ __forceinline__ float b0_thr(float dv){
  // sigmoid(x) >= dv  <=>  x >= log(dv/(1-dv))   (exact 0.0 for dv=0.5)
  if (dv <= 0.f) return -3.4e38f;
  if (dv >= 1.f) return  3.4e38f;
  return (float)log((double)dv/(1.0-(double)dv));
}

// ---------------- K1: wfeat (bn1, fp64 acc) + nodesT (bf16) ----------------
__global__ __launch_bounds__(256) void k_proj(const float* __restrict__ x,
    const float* __restrict__ w1w, const float* __restrict__ w1b,
    const float* __restrict__ g1, const float* __restrict__ be1,
    const float* __restrict__ mu1, const float* __restrict__ va1,
    const float* __restrict__ nw, const float* __restrict__ nb,
    float* __restrict__ Wt, u16* __restrict__ ndT){
  const int b = blockIdx.y;
  const int n0 = blockIdx.x*32;
  const int t = threadIdx.x;            // t = output channel
  __shared__ float xs[32][33];
  double acc1[32];
  float  acc2[32];
  #pragma unroll
  for(int i=0;i<32;i++){acc1[i]=0.0;acc2[i]=0.f;}
  const float* xb = x + (size_t)b*CINCH*NP + n0;
  for(int cb=0; cb<CINCH; cb+=32){
    __syncthreads();
    {
      int cs=t>>3, nv=(t&7)*4;
      float4 v = *(const float4*)(xb + (size_t)(cb+cs)*NP + nv);
      xs[cs][nv]=v.x; xs[cs][nv+1]=v.y; xs[cs][nv+2]=v.z; xs[cs][nv+3]=v.w;
    }
    __syncthreads();
    const float* p1 = w1w + (size_t)t*CINCH + cb;
    const float* p2 = nw  + (size_t)t*CINCH + cb;
    #pragma unroll
    for(int i0=0;i0<32;i0+=8){
      float wr1[8], wr2[8];
      #pragma unroll
      for(int i=0;i<8;i+=4){
        float4 a=*(const float4*)(p1+i0+i); wr1[i]=a.x;wr1[i+1]=a.y;wr1[i+2]=a.z;wr1[i+3]=a.w;
        float4 c=*(const float4*)(p2+i0+i); wr2[i]=c.x;wr2[i+1]=c.y;wr2[i+2]=c.z;wr2[i+3]=c.w;
      }
      #pragma unroll
      for(int i=0;i<8;i++){
        float wa=wr1[i], wb=wr2[i];
        #pragma unroll
        for(int n=0;n<32;n++){
          float xv = xs[i0+i][n];
          acc1[n] += (double)wa*(double)xv;
          acc2[n] = fmaf(wb, xv, acc2[n]);
        }
      }
    }
  }
  float inv = g1[t]*rsqrtf(va1[t]+1e-5f);
  float add = be1[t]-mu1[t]*inv;
  float b1 = w1b[t], b2 = nb[t];
  u16 nb_[32];
  #pragma unroll
  for(int n=0;n<32;n++){
    Wt[((size_t)b*NP + n0+n)*ICH + t] = ((float)(acc1[n]+(double)b1))*inv + add;
    nb_[n] = f2bf(acc2[n]+b2);
  }
  u16* np_ = ndT + ((size_t)b*ICH + t)*NP + n0;
  #pragma unroll
  for(int q=0;q<8;q++) *(ushort4*)(np_ + q*4) = *(ushort4*)&nb_[q*4];
}

// ---------------- K2: iw = Wt Wt^T / 16, fp64 accumulate, symmetric ----------------
__global__ __launch_bounds__(256) void k_iw(const float* __restrict__ Wb, float* __restrict__ ob){
  int tt = blockIdx.x;
  int bi = (int)((sqrtf(8.f*(float)tt+1.f)-1.f)*0.5f);
  while(bi*(bi+1)/2 > tt) bi--;
  while((bi+1)*(bi+2)/2 <= tt) bi++;
  int bj = tt - bi*(bi+1)/2;
  const int r0=bi*64, c0=bj*64;
  __shared__ float as_[64][33], bs_[64][33];
  const int t=threadIdx.x, tx=t&15, ty=t>>4;
  double acc[4][4];
  #pragma unroll
  for(int i=0;i<4;i++)
    #pragma unroll
    for(int j=0;j<4;j++) acc[i][j]=0.0;
  for(int k0=0;k0<ICH;k0+=32){
    __syncthreads();
    {
      int r=t>>3, kv=(t&7)*4;
      #pragma unroll
      for(int rr=r; rr<64; rr+=32){
        float4 va=*(const float4*)(Wb + (size_t)(r0+rr)*ICH + k0+kv);
        as_[rr][kv]=va.x; as_[rr][kv+1]=va.y; as_[rr][kv+2]=va.z; as_[rr][kv+3]=va.w;
        float4 vb=*(const float4*)(Wb + (size_t)(c0+rr)*ICH + k0+kv);
        bs_[rr][kv]=vb.x; bs_[rr][kv+1]=vb.y; bs_[rr][kv+2]=vb.z; bs_[rr][kv+3]=vb.w;
      }
    }
    __syncthreads();
    #pragma unroll
    for(int k=0;k<32;k++){
      float av[4], bv[4];
      #pragma unroll
      for(int i=0;i<4;i++) av[i]=as_[ty*4+i][k];
      #pragma unroll
      for(int j=0;j<4;j++) bv[j]=bs_[tx*4+j][k];
      #pragma unroll
      for(int i=0;i<4;i++)
        #pragma unroll
        for(int j=0;j<4;j++)
          acc[i][j] += (double)av[i]*(double)bv[j];
    }
  }
  #pragma unroll
  for(int i=0;i<4;i++){
    #pragma unroll
    for(int j=0;j<4;j++){
      float v = (float)(acc[i][j]*0.0625);
      ob[(size_t)(r0+ty*4+i)*NP + (c0+tx*4+j)] = v;
      if(bi!=bj) ob[(size_t)(c0+tx*4+j)*NP + (r0+ty*4+i)] = v;
    }
  }
}

// ---------------- K3: materialize b0 as bf16 {0,1} ----------------
__global__ __launch_bounds__(256) void k_b0(const float* __restrict__ iw,
    u16* __restrict__ b0, const float* __restrict__ delta){
  const float thr = b0_thr(delta[0]);
  size_t i = ((size_t)blockIdx.x*256 + threadIdx.x)*8;
  float4 v0 = *(const float4*)(iw+i);
  float4 v1 = *(const float4*)(iw+i+4);
  u16 o[8];
  o[0]=v0.x>=thr?0x3F80:0; o[1]=v0.y>=thr?0x3F80:0;
  o[2]=v0.z>=thr?0x3F80:0; o[3]=v0.w>=thr?0x3F80:0;
  o[4]=v1.x>=thr?0x3F80:0; o[5]=v1.y>=thr?0x3F80:0;
  o[6]=v1.z>=thr?0x3F80:0; o[7]=v1.w>=thr?0x3F80:0;
  *(u16x8*)(b0+i) = *(u16x8*)o;
}

// ---------------- K4: bh1 = b0 @ b0 (u16 out, exact), triangular, LDS-free ----------------
__global__ __launch_bounds__(256) void k_nn0(const u16* __restrict__ b0, u16* __restrict__ bh1){
  int tt = blockIdx.x;
  int bi = (int)((sqrtf(8.f*(float)tt+1.f)-1.f)*0.5f);
  while(bi*(bi+1)/2 > tt) bi--;
  while((bi+1)*(bi+2)/2 <= tt) bi++;
  int bj = tt - bi*(bi+1)/2;
  const int r0=bi*128, c0=bj*128;
  const int t=threadIdx.x, w=t>>6, l=t&63;
  const int wr=(w>>1)*64, wc=(w&1)*64, fr=l&15, fg=l>>4;
  const f32x4 zer={0.f,0.f,0.f,0.f};
  f32x4 acc[4][4];
  #pragma unroll
  for(int i=0;i<4;i++)
    #pragma unroll
    for(int j=0;j<4;j++) acc[i][j]=zer;
  for(int k0=0;k0<NP;k0+=32){
    bf16x8 af[4], bf_[4];
    #pragma unroll
    for(int mi=0;mi<4;mi++) af[mi]=*(const bf16x8*)(b0 + (size_t)(r0+wr+mi*16+fr)*NP + k0+fg*8);
    #pragma unroll
    for(int nj=0;nj<4;nj++) bf_[nj]=*(const bf16x8*)(b0 + (size_t)(c0+wc+nj*16+fr)*NP + k0+fg*8);
    #pragma unroll
    for(int mi=0;mi<4;mi++)
      #pragma unroll
      for(int nj=0;nj<4;nj++)
        acc[mi][nj]=__builtin_amdgcn_mfma_f32_16x16x32_bf16(af[mi],bf_[nj],acc[mi][nj],0,0,0);
  }
  #pragma unroll
  for(int mi=0;mi<4;mi++){
    #pragma unroll
    for(int nj=0;nj<4;nj++){
      int gr=r0+wr+mi*16+fg*4, gc=c0+wc+nj*16+fr;
      #pragma unroll
      for(int r=0;r<4;r++){
        u16 v=(u16)acc[mi][nj][r];
        bh1[(size_t)(gr+r)*NP+gc]=v;
        if(bi!=bj) bh1[(size_t)gc*NP+(gr+r)]=v;
      }
    }
  }
}

// ---------------- K5: bh2 = bh1 @ b0 (f32 out, exact via lo/hi split) ----------------
__global__ __launch_bounds__(256) void k_nn1(const u16* __restrict__ bh1,
    const u16* __restrict__ b0, float* __restrict__ bh2){
  int tt = blockIdx.x;
  int bi = (int)((sqrtf(8.f*(float)tt+1.f)-1.f)*0.5f);
  while(bi*(bi+1)/2 > tt) bi--;
  while((bi+1)*(bi+2)/2 <= tt) bi++;
  int bj = tt - bi*(bi+1)/2;
  const int r0=bi*128, c0=bj*128;
  const int t=threadIdx.x, w=t>>6, l=t&63;
  const int wr=(w>>1)*64, wc=(w&1)*64, fr=l&15, fg=l>>4;
  const f32x4 zer={0.f,0.f,0.f,0.f};
  f32x4 accl[4][4], acch[4][4];
  #pragma unroll
  for(int i=0;i<4;i++)
    #pragma unroll
    for(int j=0;j<4;j++){accl[i][j]=zer; acch[i][j]=zer;}
  for(int k0=0;k0<NP;k0+=32){
    bf16x8 al[4], ah[4], bf_[4];
    #pragma unroll
    for(int mi=0;mi<4;mi++){
      u16x8 u=*(const u16x8*)(bh1 + (size_t)(r0+wr+mi*16+fr)*NP + k0+fg*8);
      #pragma unroll
      for(int e=0;e<8;e++){
        unsigned v=u[e];
        al[mi][e]=(short)f2bf((float)(v&127u));
        ah[mi][e]=(short)f2bf((float)(v>>7));
      }
    }
    #pragma unroll
    for(int nj=0;nj<4;nj++) bf_[nj]=*(const bf16x8*)(b0 + (size_t)(c0+wc+nj*16+fr)*NP + k0+fg*8);
    #pragma unroll
    for(int mi=0;mi<4;mi++)
      #pragma unroll
      for(int nj=0;nj<4;nj++){
        accl[mi][nj]=__builtin_amdgcn_mfma_f32_16x16x32_bf16(al[mi],bf_[nj],accl[mi][nj],0,0,0);
        acch[mi][nj]=__builtin_amdgcn_mfma_f32_16x16x32_bf16(ah[mi],bf_[nj],acch[mi][nj],0,0,0);
      }
  }
  #pragma unroll
  for(int mi=0;mi<4;mi++){
    #pragma unroll
    for(int nj=0;nj<4;nj++){
      int gr=r0+wr+mi*16+fg*4, gc=c0+wc+nj*16+fr;
      #pragma unroll
      for(int r=0;r<4;r++){
        float v = fmaf(128.f, acch[mi][nj][r], accl[mi][nj][r]);
        bh2[(size_t)(gr+r)*NP+gc]=v;
        if(bi!=bj) bh2[(size_t)gc*NP+(gr+r)]=v;
      }
    }
  }
}

// ---------------- K6: softmax row stats. H=0 masked iw; H=1 u16 bh; H=2 f32 bh ----------------
template<int H>
__global__ __launch_bounds__(256) void k_stats(const float* __restrict__ iw,
    const u16* __restrict__ bhu, const float* __restrict__ bhf,
    const float* __restrict__ delta, float* __restrict__ mxo, float* __restrict__ invo){
  const int n=blockIdx.x, t=threadIdx.x;
  const float* ir = iw + (size_t)n*NP;
  const float thr = (H==0)? b0_thr(delta[0]) : 0.f;
  float m=-3.0e38f, s=0.f;
  for(int m0=t*4; m0<NP; m0+=1024){
    float4 v=*(const float4*)(ir+m0);
    float lg[4];
    if(H==0){
      lg[0]=v.x>=thr?v.x:0.f; lg[1]=v.y>=thr?v.y:0.f;
      lg[2]=v.z>=thr?v.z:0.f; lg[3]=v.w>=thr?v.w:0.f;
    } else if(H==1){
      ushort4 h=*(const ushort4*)(bhu + (size_t)n*NP + m0);
      lg[0]=(float)h.x*v.x; lg[1]=(float)h.y*v.y;
      lg[2]=(float)h.z*v.z; lg[3]=(float)h.w*v.w;
    } else {
      float4 h=*(const float4*)(bhf + (size_t)n*NP + m0);
      lg[0]=h.x*v.x; lg[1]=h.y*v.y; lg[2]=h.z*v.z; lg[3]=h.w*v.w;
    }
    float m4=fmaxf(fmaxf(lg[0],lg[1]),fmaxf(lg[2],lg[3]));
    if(m4>m){ s*=expf(m-m4); m=m4; }
    s += expf(lg[0]-m)+expf(lg[1]-m)+expf(lg[2]-m)+expf(lg[3]-m);
  }
  #pragma unroll
  for(int off=32; off>=1; off>>=1){
    float mo=__shfl_xor(m,off), so=__shfl_xor(s,off);
    float mn=fmaxf(m,mo);
    s = s*expf(m-mn) + so*expf(mo-mn);
    m = mn;
  }
  __shared__ float wm[4], wsum[4];
  if((t&63)==0){ wm[t>>6]=m; wsum[t>>6]=s; }
  __syncthreads();
  if(t==0){
    #pragma unroll
    for(int i=1;i<4;i++){
      float mo=wm[i], so=wsum[i];
      float mn=fmaxf(m,mo);
      s = s*expf(m-mn) + so*expf(mo-mn);
      m=mn;
    }
    mxo[n]=m; invo[n]=1.0f/s;
  }
}

// ---------------- K7: traw = softmax(logits) @ nodes, LDS-free MFMA ----------------
template<int H>
__global__ __launch_bounds__(256) void k_pv(const float* __restrict__ iw,
    const u16* __restrict__ bhu, const float* __restrict__ bhf,
    const u16* __restrict__ ndT, const float* __restrict__ mx,
    const float* __restrict__ inv, const float* __restrict__ delta,
    float* __restrict__ traw){
  const int r0 = blockIdx.x*64;
  const int t=threadIdx.x, w=t>>6, l=t&63, fr=l&15, fg=l>>4;
  const int row = r0 + w*16 + fr;
  const float thr=(H==0)?b0_thr(delta[0]):0.f;
  const float rm = mx[row], ri = inv[row];
  const f32x4 zer={0.f,0.f,0.f,0.f};
  f32x4 acc[16];
  #pragma unroll
  for(int i=0;i<16;i++) acc[i]=zer;
  const float* ip = iw + (size_t)row*NP;
  const float* fp = bhf + (size_t)row*NP;
  const u16*   up = bhu + (size_t)row*NP;
  for(int k0=0;k0<NP;k0+=32){
    const int kb = k0 + fg*8;
    float4 v0=*(const float4*)(ip+kb), v1=*(const float4*)(ip+kb+4);
    float lg[8];
    if(H==0){
      lg[0]=v0.x>=thr?v0.x:0.f; lg[1]=v0.y>=thr?v0.y:0.f;
      lg[2]=v0.z>=thr?v0.z:0.f; lg[3]=v0.w>=thr?v0.w:0.f;
      lg[4]=v1.x>=thr?v1.x:0.f; lg[5]=v1.y>=thr?v1.y:0.f;
      lg[6]=v1.z>=thr?v1.z:0.f; lg[7]=v1.w>=thr?v1.w:0.f;
    } else if(H==1){
      u16x8 h=*(const u16x8*)(up+kb);
      float4* vv0=&v0; float4* vv1=&v1;
      lg[0]=(float)h[0]*v0.x; lg[1]=(float)h[1]*v0.y;
      lg[2]=(float)h[2]*v0.z; lg[3]=(float)h[3]*v0.w;
      lg[4]=(float)h[4]*v1.x; lg[5]=(float)h[5]*v1.y;
      lg[6]=(float)h[6]*v1.z; lg[7]=(float)h[7]*v1.w;
      (void)vv0;(void)vv1;
    } else {
      float4 h0=*(const float4*)(fp+kb), h1=*(const float4*)(fp+kb+4);
      lg[0]=h0.x*v0.x; lg[1]=h0.y*v0.y; lg[2]=h0.z*v0.z; lg[3]=h0.w*v0.w;
      lg[4]=h1.x*v1.x; lg[5]=h1.y*v1.y; lg[6]=h1.z*v1.z; lg[7]=h1.w*v1.w;
    }
    bf16x8 af;
    #pragma unroll
    for(int e=0;e<8;e++) af[e]=(short)f2bf(expf(lg[e]-rm)*ri);
    #pragma unroll
    for(int nj=0;nj<16;nj++){
      bf16x8 bf_=*(const bf16x8*)(ndT + (size_t)(nj*16+fr)*NP + kb);
      acc[nj]=__builtin_amdgcn_mfma_f32_16x16x32_bf16(af,bf_,acc[nj],0,0,0);
    }
  }
  #pragma unroll
  for(int nj=0;nj<16;nj++){
    #pragma unroll
    for(int r=0;r<4;r++)
      traw[(size_t)(r0 + w*16 + fg*4 + r)*ICH + nj*16+fr] = acc[nj][r];
  }
}

// ---------------- K8: tail GEMMs (fp32 vector), per batch ----------------
// MODE 0: hop conv  -> hcat[n][coff+oc] (ldc 768)
// MODE 1: fuse+bnf  -> xp[n][oc]
// MODE 2: res+bnr   -> out[oc][n] (transposed), K=512 = [x[:256] | xp]
template<int MODE>
__global__ __launch_bounds__(256) void k_tail(const float* __restrict__ A,
    const float* __restrict__ Bw, const float* __restrict__ bias,
    const float* __restrict__ xsrc,
    const float* __restrict__ g, const float* __restrict__ be,
    const float* __restrict__ mu, const float* __restrict__ va,
    float* __restrict__ Cout, int coff){
  constexpr int K   = MODE==0?256:(MODE==1?768:512);
  constexpr int LDA = MODE==1?768:256;
  const int n0=blockIdx.x*64, c0=blockIdx.y*64;
  __shared__ float as_[64][33], bs_[64][33];
  const int t=threadIdx.x, tx=t&15, ty=t>>4;
  float acc[4][4];
  #pragma unroll
  for(int i=0;i<4;i++)
    #pragma unroll
    for(int j=0;j<4;j++) acc[i][j]=0.f;
  for(int k0=0;k0<K;k0+=32){
    __syncthreads();
    if(MODE==2 && k0<256){
      int k=t>>4, nv=(t&15)*4;
      #pragma unroll
      for(int kk=k;kk<32;kk+=16){
        float4 v=*(const float4*)(xsrc + (size_t)(k0+kk)*NP + n0+nv);
        as_[nv+0][kk]=v.x; as_[nv+1][kk]=v.y; as_[nv+2][kk]=v.z; as_[nv+3][kk]=v.w;
      }
    } else {
      int kb = (MODE==2)? k0-256 : k0;
      int r=t>>3, kv=(t&7)*4;
      #pragma unroll
      for(int rr=r;rr<64;rr+=32){
        float4 v=*(const float4*)(A + (size_t)(n0+rr)*LDA + kb+kv);
        as_[rr][kv]=v.x; as_[rr][kv+1]=v.y; as_[rr][kv+2]=v.z; as_[rr][kv+3]=v.w;
      }
    }
    {
      int r=t>>3, kv=(t&7)*4;
      #pragma unroll
      for(int rr=r;rr<64;rr+=32){
        float4 v=*(const float4*)(Bw + (size_t)(c0+rr)*K + k0+kv);
        bs_[rr][kv]=v.x; bs_[rr][kv+1]=v.y; bs_[rr][kv+2]=v.z; bs_[rr][kv+3]=v.w;
      }
    }
    __syncthreads();
    #pragma unroll
    for(int k=0;k<32;k++){
      float av[4],bv[4];
      #pragma unroll
      for(int i=0;i<4;i++) av[i]=as_[ty*4+i][k];
      #pragma unroll
      for(int j=0;j<4;j++) bv[j]=bs_[tx*4+j][k];
      #pragma unroll
      for(int i=0;i<4;i++)
        #pragma unroll
        for(int j=0;j<4;j++) acc[i][j]+=av[i]*bv[j];
    }
  }
  const int col=c0+tx*4, row=n0+ty*4;
  float sc[4], ad[4];
  #pragma unroll
  for(int j=0;j<4;j++){
    int c=col+j;
    if(MODE==0){ sc[j]=1.f; ad[j]=bias[c]; }
    else {
      float iv=g[c]*rsqrtf(va[c]+1e-5f);
      sc[j]=iv; ad[j]=be[c]-mu[c]*iv + bias[c]*iv;
    }
  }
  if(MODE==2){
    #pragma unroll
    for(int j=0;j<4;j++){
      float4 ov;
      ov.x=acc[0][j]*sc[j]+ad[j]; ov.y=acc[1][j]*sc[j]+ad[j];
      ov.z=acc[2][j]*sc[j]+ad[j]; ov.w=acc[3][j]*sc[j]+ad[j];
      *(float4*)(Cout + (size_t)(col+j)*NP + row) = ov;
    }
  } else {
    const int ldc = MODE==0? 3*ICH : ICH;
    #pragma unroll
    for(int i=0;i<4;i++){
      float4 ov;
      ov.x=acc[i][0]*sc[0]+ad[0]; ov.y=acc[i][1]*sc[1]+ad[1];
      ov.z=acc[i][2]*sc[2]+ad[2]; ov.w=acc[i][3]*sc[3]+ad[3];
      *(float4*)(Cout + (size_t)(n0+ty*4+i)*ldc + coff + col) = ov;
    }
  }
}

__global__ void k_diag(float* out, int n, float val){
  int i = blockIdx.x*256 + threadIdx.x;
  if(i<n) out[i] = (i==0)? val : 0.f;
}

extern "C" void kernel_launch(void* const* d_in, const int* in_sizes, int n_in,
                              void* d_out, int out_size, void* d_ws, size_t ws_size,
                              hipStream_t stream){
  const float* x    =(const float*)d_in[0];
  const float* delta=(const float*)d_in[1];
  const float* w1w  =(const float*)d_in[2];
  const float* w1b  =(const float*)d_in[3];
  const float* g1   =(const float*)d_in[4];
  const float* be1  =(const float*)d_in[5];
  const float* mu1  =(const float*)d_in[6];
  const float* va1  =(const float*)d_in[7];
  const float* nw   =(const float*)d_in[8];
  const float* nb   =(const float*)d_in[9];
  const float* hw   =(const float*)d_in[10];
  const float* hb   =(const float*)d_in[11];
  const float* fw   =(const float*)d_in[12];
  const float* fb   =(const float*)d_in[13];
  const float* gf   =(const float*)d_in[14];
  const float* bef  =(const float*)d_in[15];
  const float* muf  =(const float*)d_in[16];
  const float* vaf  =(const float*)d_in[17];
  const float* rw   =(const float*)d_in[18];
  const float* rb   =(const float*)d_in[19];
  const float* gr   =(const float*)d_in[20];
  const float* ber  =(const float*)d_in[21];
  const float* mur  =(const float*)d_in[22];
  const float* var_ =(const float*)d_in[23];
  float* out=(float*)d_out;

  char* ws=(char*)d_ws;
  size_t o=0;
  auto alloc=[&](size_t bytes)->char*{ char* p=ws+o; o+=(bytes+255)&~(size_t)255; return p; };
  const size_t NN=(size_t)NP*NP;
  float* Wt    =(float*)alloc((size_t)BB*NP*ICH*4);   // [B][N][IC]
  u16*   ndT   =(u16*)  alloc((size_t)BB*ICH*NP*2);   // [B][IC][N] bf16
  float* iw    =(float*)alloc(NN*4);                  // per-batch
  u16*   b0    =(u16*)  alloc(NN*2);                  // per-batch bf16
  u16*   bh1   =(u16*)  alloc(NN*2);                  // per-batch u16 (exact <=4096)
  float* bh2   =(float*)alloc(NN*4);                  // per-batch f32 (exact <=2^24)
  float* traw  =(float*)alloc((size_t)NP*ICH*4);
  float* hcat  =(float*)alloc((size_t)NP*3*ICH*4);
  float* xp    =(float*)alloc((size_t)NP*ICH*4);
  float* mx    =(float*)alloc((size_t)NP*4);
  float* inv   =(float*)alloc((size_t)NP*4);
  if(o > ws_size){
    k_diag<<<dim3((out_size+255)/256),dim3(256),0,stream>>>(out, out_size, (float)ws_size);
    return;
  }
  dim3 blk(256);
  k_proj<<<dim3(NP/32,BB),blk,0,stream>>>(x,w1w,w1b,g1,be1,mu1,va1,nw,nb,Wt,ndT);
  for(int b=0;b<BB;b++){
    const float* Wt_b  = Wt + (size_t)b*NP*ICH;
    const u16*   ndT_b = ndT + (size_t)b*ICH*NP;
    const float* x_b   = x + (size_t)b*CINCH*NP;
    float*       out_b = out + (size_t)b*CINCH*NP;
    k_iw <<<dim3(2080),blk,0,stream>>>(Wt_b,iw);
    k_b0 <<<dim3(8192),blk,0,stream>>>(iw,b0,delta);
    k_nn0<<<dim3(528),blk,0,stream>>>(b0,bh1);
    k_nn1<<<dim3(528),blk,0,stream>>>(bh1,b0,bh2);
    // hop 0
    k_stats<0><<<dim3(NP),blk,0,stream>>>(iw,bh1,bh2,delta,mx,inv);
    k_pv<0>   <<<dim3(64),blk,0,stream>>>(iw,bh1,bh2,ndT_b,mx,inv,delta,traw);
    k_tail<0> <<<dim3(64,4),blk,0,stream>>>(traw,hw+0*ICH*ICH,hb+0*ICH,nullptr,nullptr,nullptr,nullptr,nullptr,hcat,0);
    // hop 1
    k_stats<1><<<dim3(NP),blk,0,stream>>>(iw,bh1,bh2,delta,mx,inv);
    k_pv<1>   <<<dim3(64),blk,0,stream>>>(iw,bh1,bh2,ndT_b,mx,inv,delta,traw);
    k_tail<0> <<<dim3(64,4),blk,0,stream>>>(traw,hw+1*ICH*ICH,hb+1*ICH,nullptr,nullptr,nullptr,nullptr,nullptr,hcat,ICH);
    // hop 2
    k_stats<2><<<dim3(NP),blk,0,stream>>>(iw,bh1,bh2,delta,mx,inv);
    k_pv<2>   <<<dim3(64),blk,0,stream>>>(iw,bh1,bh2,ndT_b,mx,inv,delta,traw);
    k_tail<0> <<<dim3(64,4),blk,0,stream>>>(traw,hw+2*ICH*ICH,hb+2*ICH,nullptr,nullptr,nullptr,nullptr,nullptr,hcat,2*ICH);
    // fuse + bnf ; res + bnr
    k_tail<1> <<<dim3(64,4),blk,0,stream>>>(hcat,fw,fb,nullptr,gf,bef,muf,vaf,xp,0);
    k_tail<2> <<<dim3(64,8),blk,0,stream>>>(xp,rw,rb,x_b,gr,ber,mur,var_,out_b,0);
  }
}

// Round 3
// 6184.399 us; speedup vs baseline: 2.0683x; 2.0683x over previous
//
#include <hip/hip_runtime.h>

#define CINCH 512
#define ICH 256
#define NP 4096
#define BB 4

typedef __attribute__((ext_vector_type(8))) short bf16x8;
typedef __attribute__((ext_vector_type(8))) unsigned short u16x8;
typedef __attribute__((ext_vector_type(4))) float f32x4;
typedef unsigned short u16;

__device__ __forceinline__ u16 f2bf(float f){
  unsigned u = __builtin_bit_cast(unsigned, f);
  u += 0x7FFFu + ((u>>16)&1u);
  return (u16)(u>>16);
}

__device__ __forceinline__ float b0_thr(float dv){
  if (dv <= 0.f) return -3.4e38f;
  if (dv >= 1.f) return  3.4e38f;
  return (float)log((double)dv/(1.0-(double)dv));
}

// ---------------- K1: wfeat (bn1, fp64 acc) + nodesT (bf16) ----------------
__global__ __launch_bounds__(256) void k_proj(const float* __restrict__ x,
    const float* __restrict__ w1w, const float* __restrict__ w1b,
    const float* __restrict__ g1, const float* __restrict__ be1,
    const float* __restrict__ mu1, const float* __restrict__ va1,
    const float* __restrict__ nw, const float* __restrict__ nb,
    float* __restrict__ Wt, u16* __restrict__ ndT){
  const int b = blockIdx.y;
  const int n0 = blockIdx.x*32;
  const int t = threadIdx.x;
  __shared__ float xs[32][33];
  double acc1[32];
  float  acc2[32];
  #pragma unroll
  for(int i=0;i<32;i++){acc1[i]=0.0;acc2[i]=0.f;}
  const float* xb = x + (size_t)b*CINCH*NP + n0;
  for(int cb=0; cb<CINCH; cb+=32){
    __syncthreads();
    {
      int cs=t>>3, nv=(t&7)*4;
      float4 v = *(const float4*)(xb + (size_t)(cb+cs)*NP + nv);
      xs[cs][nv]=v.x; xs[cs][nv+1]=v.y; xs[cs][nv+2]=v.z; xs[cs][nv+3]=v.w;
    }
    __syncthreads();
    const float* p1 = w1w + (size_t)t*CINCH + cb;
    const float* p2 = nw  + (size_t)t*CINCH + cb;
    #pragma unroll
    for(int i0=0;i0<32;i0+=8){
      float wr1[8], wr2[8];
      #pragma unroll
      for(int i=0;i<8;i+=4){
        float4 a=*(const float4*)(p1+i0+i); wr1[i]=a.x;wr1[i+1]=a.y;wr1[i+2]=a.z;wr1[i+3]=a.w;
        float4 c=*(const float4*)(p2+i0+i); wr2[i]=c.x;wr2[i+1]=c.y;wr2[i+2]=c.z;wr2[i+3]=c.w;
      }
      #pragma unroll
      for(int i=0;i<8;i++){
        float wa=wr1[i], wb=wr2[i];
        #pragma unroll
        for(int n=0;n<32;n++){
          float xv = xs[i0+i][n];
          acc1[n] += (double)wa*(double)xv;
          acc2[n] = fmaf(wb, xv, acc2[n]);
        }
      }
    }
  }
  float inv = g1[t]*rsqrtf(va1[t]+1e-5f);
  float add = be1[t]-mu1[t]*inv;
  float b1 = w1b[t], b2 = nb[t];
  u16 nb_[32];
  #pragma unroll
  for(int n=0;n<32;n++){
    Wt[((size_t)b*NP + n0+n)*ICH + t] = ((float)(acc1[n]+(double)b1))*inv + add;
    nb_[n] = f2bf(acc2[n]+b2);
  }
  u16* np_ = ndT + ((size_t)b*ICH + t)*NP + n0;
  #pragma unroll
  for(int q=0;q<8;q++) *(ushort4*)(np_ + q*4) = *(ushort4*)&nb_[q*4];
}

// ---------------- K2: iw = Wt Wt^T / 16, fp64 accumulate, symmetric ----------------
__global__ __launch_bounds__(256) void k_iw(const float* __restrict__ Wb, float* __restrict__ ob){
  int tt = blockIdx.x;
  int bi = (int)((sqrtf(8.f*(float)tt+1.f)-1.f)*0.5f);
  while(bi*(bi+1)/2 > tt) bi--;
  while((bi+1)*(bi+2)/2 <= tt) bi++;
  int bj = tt - bi*(bi+1)/2;
  const int r0=bi*64, c0=bj*64;
  __shared__ float as_[64][33], bs_[64][33];
  const int t=threadIdx.x, tx=t&15, ty=t>>4;
  double acc[4][4];
  #pragma unroll
  for(int i=0;i<4;i++)
    #pragma unroll
    for(int j=0;j<4;j++) acc[i][j]=0.0;
  for(int k0=0;k0<ICH;k0+=32){
    __syncthreads();
    {
      int r=t>>3, kv=(t&7)*4;
      #pragma unroll
      for(int rr=r; rr<64; rr+=32){
        float4 va=*(const float4*)(Wb + (size_t)(r0+rr)*ICH + k0+kv);
        as_[rr][kv]=va.x; as_[rr][kv+1]=va.y; as_[rr][kv+2]=va.z; as_[rr][kv+3]=va.w;
        float4 vb=*(const float4*)(Wb + (size_t)(c0+rr)*ICH + k0+kv);
        bs_[rr][kv]=vb.x; bs_[rr][kv+1]=vb.y; bs_[rr][kv+2]=vb.z; bs_[rr][kv+3]=vb.w;
      }
    }
    __syncthreads();
    #pragma unroll
    for(int k=0;k<32;k++){
      float av[4], bv[4];
      #pragma unroll
      for(int i=0;i<4;i++) av[i]=as_[ty*4+i][k];
      #pragma unroll
      for(int j=0;j<4;j++) bv[j]=bs_[tx*4+j][k];
      #pragma unroll
      for(int i=0;i<4;i++)
        #pragma unroll
        for(int j=0;j<4;j++)
          acc[i][j] += (double)av[i]*(double)bv[j];
    }
  }
  #pragma unroll
  for(int i=0;i<4;i++){
    #pragma unroll
    for(int j=0;j<4;j++){
      float v = (float)(acc[i][j]*0.0625);
      ob[(size_t)(r0+ty*4+i)*NP + (c0+tx*4+j)] = v;
      if(bi!=bj) ob[(size_t)(c0+tx*4+j)*NP + (r0+ty*4+i)] = v;
    }
  }
}

// ---------------- K3: materialize b0 as bf16 {0,1} ----------------
__global__ __launch_bounds__(256) void k_b0(const float* __restrict__ iw,
    u16* __restrict__ b0, const float* __restrict__ delta){
  const float thr = b0_thr(delta[0]);
  size_t i = ((size_t)blockIdx.x*256 + threadIdx.x)*8;
  float4 v0 = *(const float4*)(iw+i);
  float4 v1 = *(const float4*)(iw+i+4);
  u16 o[8];
  o[0]=v0.x>=thr?0x3F80:0; o[1]=v0.y>=thr?0x3F80:0;
  o[2]=v0.z>=thr?0x3F80:0; o[3]=v0.w>=thr?0x3F80:0;
  o[4]=v1.x>=thr?0x3F80:0; o[5]=v1.y>=thr?0x3F80:0;
  o[6]=v1.z>=thr?0x3F80:0; o[7]=v1.w>=thr?0x3F80:0;
  *(u16x8*)(b0+i) = *(u16x8*)o;
}

// ---------------- K4: bh1 = b0 @ b0 (u16 out, exact), triangular ----------------
__global__ __launch_bounds__(256) void k_nn0(const u16* __restrict__ b0, u16* __restrict__ bh1){
  int tt = blockIdx.x;
  int bi = (int)((sqrtf(8.f*(float)tt+1.f)-1.f)*0.5f);
  while(bi*(bi+1)/2 > tt) bi--;
  while((bi+1)*(bi+2)/2 <= tt) bi++;
  int bj = tt - bi*(bi+1)/2;
  const int r0=bi*128, c0=bj*128;
  const int t=threadIdx.x, w=t>>6, l=t&63;
  const int wr=(w>>1)*64, wc=(w&1)*64, fr=l&15, fg=l>>4;
  const f32x4 zer={0.f,0.f,0.f,0.f};
  f32x4 acc[4][4];
  #pragma unroll
  for(int i=0;i<4;i++)
    #pragma unroll
    for(int j=0;j<4;j++) acc[i][j]=zer;
  for(int k0=0;k0<NP;k0+=32){
    bf16x8 af[4], bf_[4];
    #pragma unroll
    for(int mi=0;mi<4;mi++) af[mi]=*(const bf16x8*)(b0 + (size_t)(r0+wr+mi*16+fr)*NP + k0+fg*8);
    #pragma unroll
    for(int nj=0;nj<4;nj++) bf_[nj]=*(const bf16x8*)(b0 + (size_t)(c0+wc+nj*16+fr)*NP + k0+fg*8);
    #pragma unroll
    for(int mi=0;mi<4;mi++)
      #pragma unroll
      for(int nj=0;nj<4;nj++)
        acc[mi][nj]=__builtin_amdgcn_mfma_f32_16x16x32_bf16(af[mi],bf_[nj],acc[mi][nj],0,0,0);
  }
  #pragma unroll
  for(int mi=0;mi<4;mi++){
    #pragma unroll
    for(int nj=0;nj<4;nj++){
      int gr=r0+wr+mi*16+fg*4, gc=c0+wc+nj*16+fr;
      #pragma unroll
      for(int r=0;r<4;r++){
        u16 v=(u16)acc[mi][nj][r];
        bh1[(size_t)(gr+r)*NP+gc]=v;
        if(bi!=bj) bh1[(size_t)gc*NP+(gr+r)]=v;
      }
    }
  }
}

// ---------------- K5: bh2 = bh1 @ b0 (f32 out, exact via lo/hi split) ----------------
__global__ __launch_bounds__(256) void k_nn1(const u16* __restrict__ bh1,
    const u16* __restrict__ b0, float* __restrict__ bh2){
  int tt = blockIdx.x;
  int bi = (int)((sqrtf(8.f*(float)tt+1.f)-1.f)*0.5f);
  while(bi*(bi+1)/2 > tt) bi--;
  while((bi+1)*(bi+2)/2 <= tt) bi++;
  int bj = tt - bi*(bi+1)/2;
  const int r0=bi*128, c0=bj*128;
  const int t=threadIdx.x, w=t>>6, l=t&63;
  const int wr=(w>>1)*64, wc=(w&1)*64, fr=l&15, fg=l>>4;
  const f32x4 zer={0.f,0.f,0.f,0.f};
  f32x4 accl[4][4], acch[4][4];
  #pragma unroll
  for(int i=0;i<4;i++)
    #pragma unroll
    for(int j=0;j<4;j++){accl[i][j]=zer; acch[i][j]=zer;}
  for(int k0=0;k0<NP;k0+=32){
    bf16x8 al[4], ah[4], bf_[4];
    #pragma unroll
    for(int mi=0;mi<4;mi++){
      u16x8 u=*(const u16x8*)(bh1 + (size_t)(r0+wr+mi*16+fr)*NP + k0+fg*8);
      #pragma unroll
      for(int e=0;e<8;e++){
        unsigned v=u[e];
        al[mi][e]=(short)f2bf((float)(v&127u));
        ah[mi][e]=(short)f2bf((float)(v>>7));
      }
    }
    #pragma unroll
    for(int nj=0;nj<4;nj++) bf_[nj]=*(const bf16x8*)(b0 + (size_t)(c0+wc+nj*16+fr)*NP + k0+fg*8);
    #pragma unroll
    for(int mi=0;mi<4;mi++)
      #pragma unroll
      for(int nj=0;nj<4;nj++){
        accl[mi][nj]=__builtin_amdgcn_mfma_f32_16x16x32_bf16(al[mi],bf_[nj],accl[mi][nj],0,0,0);
        acch[mi][nj]=__builtin_amdgcn_mfma_f32_16x16x32_bf16(ah[mi],bf_[nj],acch[mi][nj],0,0,0);
      }
  }
  #pragma unroll
  for(int mi=0;mi<4;mi++){
    #pragma unroll
    for(int nj=0;nj<4;nj++){
      int gr=r0+wr+mi*16+fg*4, gc=c0+wc+nj*16+fr;
      #pragma unroll
      for(int r=0;r<4;r++){
        float v = fmaf(128.f, acch[mi][nj][r], accl[mi][nj][r]);
        bh2[(size_t)(gr+r)*NP+gc]=v;
        if(bi!=bj) bh2[(size_t)gc*NP+(gr+r)]=v;
      }
    }
  }
}

// ---------------- K6: fused flash-style softmax @ nodes, 3 hops in one grid ----------------
template<int H>
__device__ __forceinline__ void pv_body(const float* __restrict__ iw,
    const u16* __restrict__ bh1, const float* __restrict__ bh2,
    const u16* __restrict__ ndT, const float* __restrict__ delta,
    float* __restrict__ traw){
  const int rs = blockIdx.x;                 // 16-row set
  const int t = threadIdx.x, w = t>>6, l = t&63, fr = l&15, fg = l>>4;
  const int row = rs*16 + fr;
  const int kbase = w*1024;                  // per-wave K quarter
  const float thr = b0_thr(delta[0]);
  const f32x4 zer={0.f,0.f,0.f,0.f};
  f32x4 acc[16];
  #pragma unroll
  for(int i=0;i<16;i++) acc[i]=zer;
  float m_run=-3.0e38f, s_run=0.f;
  const float* ip = iw  + (size_t)row*NP + kbase;
  const u16*   up = bh1 + (size_t)row*NP + kbase;
  const float* fp = bh2 + (size_t)row*NP + kbase;
  for(int k0=0;k0<1024;k0+=32){
    const int kb = k0 + fg*8;
    // preload all 16 B fragments (independent L2 loads)
    bf16x8 bfr[16];
    #pragma unroll
    for(int nj=0;nj<16;nj++)
      bfr[nj]=*(const bf16x8*)(ndT + (size_t)(nj*16+fr)*NP + kbase + kb);
    // logits for row fr, k slice
    float lg[8];
    {
      float4 v0=*(const float4*)(ip+kb), v1=*(const float4*)(ip+kb+4);
      if(H==0){
        lg[0]=v0.x>=thr?v0.x:0.f; lg[1]=v0.y>=thr?v0.y:0.f;
        lg[2]=v0.z>=thr?v0.z:0.f; lg[3]=v0.w>=thr?v0.w:0.f;
        lg[4]=v1.x>=thr?v1.x:0.f; lg[5]=v1.y>=thr?v1.y:0.f;
        lg[6]=v1.z>=thr?v1.z:0.f; lg[7]=v1.w>=thr?v1.w:0.f;
      } else if(H==1){
        u16x8 h=*(const u16x8*)(up+kb);
        lg[0]=(float)h[0]*v0.x; lg[1]=(float)h[1]*v0.y;
        lg[2]=(float)h[2]*v0.z; lg[3]=(float)h[3]*v0.w;
        lg[4]=(float)h[4]*v1.x; lg[5]=(float)h[5]*v1.y;
        lg[6]=(float)h[6]*v1.z; lg[7]=(float)h[7]*v1.w;
      } else {
        float4 h0=*(const float4*)(fp+kb), h1=*(const float4*)(fp+kb+4);
        lg[0]=h0.x*v0.x; lg[1]=h0.y*v0.y; lg[2]=h0.z*v0.z; lg[3]=h0.w*v0.w;
        lg[4]=h1.x*v1.x; lg[5]=h1.y*v1.y; lg[6]=h1.z*v1.z; lg[7]=h1.w*v1.w;
      }
    }
    float m_t = fmaxf(fmaxf(fmaxf(lg[0],lg[1]),fmaxf(lg[2],lg[3])),
                      fmaxf(fmaxf(lg[4],lg[5]),fmaxf(lg[6],lg[7])));
    m_t = fmaxf(m_t, __shfl_xor(m_t,16));
    m_t = fmaxf(m_t, __shfl_xor(m_t,32));     // row max over this 32-k tile
    if(__any(m_t > m_run + 6.0f)){
      float m_new = fmaxf(m_run, m_t);
      float sc = __expf(m_run - m_new);        // exp(-inf)=0 first time
      s_run *= sc;
      #pragma unroll
      for(int r=0;r<4;r++){
        float scr = __shfl(sc, fg*4+r);        // scale for this lane's C rows
        #pragma unroll
        for(int nj=0;nj<16;nj++) acc[nj][r]*=scr;
      }
      m_run = m_new;
    }
    bf16x8 af; float ss=0.f;
    #pragma unroll
    for(int e=0;e<8;e++){
      float p=__expf(lg[e]-m_run); ss+=p;
      af[e]=(short)f2bf(p);
    }
    s_run += ss;
    #pragma unroll
    for(int nj=0;nj<16;nj++)
      acc[nj]=__builtin_amdgcn_mfma_f32_16x16x32_bf16(af,bfr[nj],acc[nj],0,0,0);
  }
  // full row sum over fg lanes
  s_run += __shfl_xor(s_run,16);
  s_run += __shfl_xor(s_run,32);
  // ---- cross-wave merge (waves = K quarters) ----
  __shared__ float Lm[4][16], Ls[4][16];
  __shared__ float Lacc[2][16][4][64];      // 32 KB
  if(fg==0) Lm[w][fr]=m_run;
  __syncthreads();
  float f_c[4];
  #pragma unroll
  for(int r=0;r<4;r++){
    int rr=fg*4+r;
    float ms=fmaxf(fmaxf(Lm[0][rr],Lm[1][rr]),fmaxf(Lm[2][rr],Lm[3][rr]));
    f_c[r]=__expf(Lm[w][rr]-ms);
  }
  {
    float ms=fmaxf(fmaxf(Lm[0][fr],Lm[1][fr]),fmaxf(Lm[2][fr],Lm[3][fr]));
    float fs=__expf(Lm[w][fr]-ms);
    if(fg==0) Ls[w][fr]=s_run*fs;
  }
  #pragma unroll
  for(int nj=0;nj<16;nj++)
    #pragma unroll
    for(int r=0;r<4;r++) acc[nj][r]*=f_c[r];
  if(w==1||w==3){
    int Ri=(w==1)?0:1;
    #pragma unroll
    for(int nj=0;nj<16;nj++)
      #pragma unroll
      for(int r=0;r<4;r++) Lacc[Ri][nj][r][l]=acc[nj][r];
  }
  __syncthreads();
  if(w==0||w==2){
    int Ri=(w==0)?0:1;
    #pragma unroll
    for(int nj=0;nj<16;nj++)
      #pragma unroll
      for(int r=0;r<4;r++) acc[nj][r]+=Lacc[Ri][nj][r][l];
  }
  __syncthreads();
  if(w==2){
    #pragma unroll
    for(int nj=0;nj<16;nj++)
      #pragma unroll
      for(int r=0;r<4;r++) Lacc[0][nj][r][l]=acc[nj][r];
  }
  __syncthreads();
  if(w==0){
    float sst[4];
    #pragma unroll
    for(int r=0;r<4;r++){
      int rr=fg*4+r;
      sst[r]=1.0f/(Ls[0][rr]+Ls[1][rr]+Ls[2][rr]+Ls[3][rr]);
    }
    #pragma unroll
    for(int nj=0;nj<16;nj++)
      #pragma unroll
      for(int r=0;r<4;r++){
        float v=(acc[nj][r]+Lacc[0][nj][r][l])*sst[r];
        traw[(size_t)(rs*16+fg*4+r)*ICH + nj*16+fr]=v;
      }
  }
}

__global__ __launch_bounds__(256) void k_pv3(const float* __restrict__ iw,
    const u16* __restrict__ bh1, const float* __restrict__ bh2,
    const u16* __restrict__ ndT, const float* __restrict__ delta,
    float* __restrict__ trawcat){
  float* traw = trawcat + (size_t)blockIdx.y*NP*ICH;
  if(blockIdx.y==0)      pv_body<0>(iw,bh1,bh2,ndT,delta,traw);
  else if(blockIdx.y==1) pv_body<1>(iw,bh1,bh2,ndT,delta,traw);
  else                   pv_body<2>(iw,bh1,bh2,ndT,delta,traw);
}

// ---------------- prep: fold hop/fuse/bnf into res GEMM ----------------
// G[i][oc][c] = sum_j fw[oc][i*256+j]*hw[i][j][c];  cf/sf/tf vectors
__global__ __launch_bounds__(256) void k_prepA(const float* __restrict__ fw,
    const float* __restrict__ hw, const float* __restrict__ hb,
    const float* __restrict__ fb,
    const float* __restrict__ gf, const float* __restrict__ bef,
    const float* __restrict__ muf, const float* __restrict__ vaf,
    float* __restrict__ G, float* __restrict__ cf,
    float* __restrict__ sf, float* __restrict__ tf){
  const int t=threadIdx.x;
  if(blockIdx.x<768){
    int i=blockIdx.x>>8, oc=blockIdx.x&255;
    float s=0.f;
    const float* fr_=fw + (size_t)oc*768 + i*256;
    const float* hp=hw + (size_t)i*ICH*ICH + t;
    for(int j=0;j<256;j++) s=fmaf(fr_[j], hp[(size_t)j*ICH], s);
    G[((size_t)i*ICH + oc)*ICH + t]=s;
  } else {
    float iv=gf[t]*rsqrtf(vaf[t]+1e-5f);
    sf[t]=iv;
    tf[t]=bef[t]-muf[t]*iv;
    float s=fb[t];
    const float* fr_=fw + (size_t)t*768;
    for(int k=0;k<768;k++) s=fmaf(fr_[k], hb[k], s);
    cf[t]=s;
  }
}

// Wcat[oc][0:256]=rw[oc][0:256]; Wcat[oc][256+i*256+c]=sum_m rw[oc][256+m]*sf[m]*G[i][m][c]
// e[oc]=sum_m rw[oc][256+m]*(sf[m]*cf[m]+tf[m]) + rb[oc]
__global__ __launch_bounds__(256) void k_prepB(const float* __restrict__ rw,
    const float* __restrict__ rb, const float* __restrict__ G,
    const float* __restrict__ cf, const float* __restrict__ sf,
    const float* __restrict__ tf, float* __restrict__ Wcat,
    float* __restrict__ evec){
  const int oc=blockIdx.x, t=threadIdx.x;
  __shared__ float rs_[256], rw2_[256];
  rw2_[t]=rw[(size_t)oc*512 + 256 + t];
  rs_[t]=rw2_[t]*sf[t];
  __syncthreads();
  Wcat[(size_t)oc*1024 + t] = rw[(size_t)oc*512 + t];
  #pragma unroll
  for(int i=0;i<3;i++){
    float s=0.f;
    const float* gp=G + (size_t)i*ICH*ICH + t;
    for(int m=0;m<256;m++) s=fmaf(rs_[m], gp[(size_t)m*ICH], s);
    Wcat[(size_t)oc*1024 + 256 + i*256 + t]=s;
  }
  if(t==0){
    float s=rb[oc];
    for(int m=0;m<256;m++) s=fmaf(rs_[m],cf[m],s)+rw2_[m]*tf[m];
    evec[oc]=s;
  }
}

// ---------------- tail: out = bnr( R0@x256 + Wcat_hops@trawcat + e ) ----------------
__global__ __launch_bounds__(256) void k_tail2(const float* __restrict__ trawcat,
    const float* __restrict__ Wcat, const float* __restrict__ evec,
    const float* __restrict__ xsrc,
    const float* __restrict__ g, const float* __restrict__ be,
    const float* __restrict__ mu, const float* __restrict__ va,
    float* __restrict__ Cout){
  const int n0=blockIdx.x*64, c0=blockIdx.y*64;
  __shared__ float as_[64][33], bs_[64][33];
  const int t=threadIdx.x, tx=t&15, ty=t>>4;
  float acc[4][4];
  #pragma unroll
  for(int i=0;i<4;i++)
    #pragma unroll
    for(int j=0;j<4;j++) acc[i][j]=0.f;
  for(int k0=0;k0<1024;k0+=32){
    __syncthreads();
    if(k0<256){
      int k=t>>4, nv=(t&15)*4;
      #pragma unroll
      for(int kk=k;kk<32;kk+=16){
        float4 v=*(const float4*)(xsrc + (size_t)(k0+kk)*NP + n0+nv);
        as_[nv+0][kk]=v.x; as_[nv+1][kk]=v.y; as_[nv+2][kk]=v.z; as_[nv+3][kk]=v.w;
      }
    } else {
      int hop=(k0-256)>>8, kk0=(k0-256)&255;
      const float* A=trawcat + (size_t)hop*NP*ICH;
      int r=t>>3, kv=(t&7)*4;
      #pragma unroll
      for(int rr=r;rr<64;rr+=32){
        float4 v=*(const float4*)(A + (size_t)(n0+rr)*ICH + kk0+kv);
        as_[rr][kv]=v.x; as_[rr][kv+1]=v.y; as_[rr][kv+2]=v.z; as_[rr][kv+3]=v.w;
      }
    }
    {
      int r=t>>3, kv=(t&7)*4;
      #pragma unroll
      for(int rr=r;rr<64;rr+=32){
        float4 v=*(const float4*)(Wcat + (size_t)(c0+rr)*1024 + k0+kv);
        bs_[rr][kv]=v.x; bs_[rr][kv+1]=v.y; bs_[rr][kv+2]=v.z; bs_[rr][kv+3]=v.w;
      }
    }
    __syncthreads();
    #pragma unroll
    for(int k=0;k<32;k++){
      float av[4],bv[4];
      #pragma unroll
      for(int i=0;i<4;i++) av[i]=as_[ty*4+i][k];
      #pragma unroll
      for(int j=0;j<4;j++) bv[j]=bs_[tx*4+j][k];
      #pragma unroll
      for(int i=0;i<4;i++)
        #pragma unroll
        for(int j=0;j<4;j++) acc[i][j]+=av[i]*bv[j];
    }
  }
  const int col=c0+tx*4, row=n0+ty*4;
  float sc[4], ad[4];
  #pragma unroll
  for(int j=0;j<4;j++){
    int c=col+j;
    float iv=g[c]*rsqrtf(va[c]+1e-5f);
    sc[j]=iv; ad[j]=be[c]-mu[c]*iv + evec[c]*iv;
  }
  #pragma unroll
  for(int j=0;j<4;j++){
    float4 ov;
    ov.x=acc[0][j]*sc[j]+ad[j]; ov.y=acc[1][j]*sc[j]+ad[j];
    ov.z=acc[2][j]*sc[j]+ad[j]; ov.w=acc[3][j]*sc[j]+ad[j];
    *(float4*)(Cout + (size_t)(col+j)*NP + row) = ov;
  }
}

__global__ void k_diag(float* out, int n, float val){
  int i = blockIdx.x*256 + threadIdx.x;
  if(i<n) out[i] = (i==0)? val : 0.f;
}

extern "C" void kernel_launch(void* const* d_in, const int* in_sizes, int n_in,
                              void* d_out, int out_size, void* d_ws, size_t ws_size,
                              hipStream_t stream){
  const float* x    =(const float*)d_in[0];
  const float* delta=(const float*)d_in[1];
  const float* w1w  =(const float*)d_in[2];
  const float* w1b  =(const float*)d_in[3];
  const float* g1   =(const float*)d_in[4];
  const float* be1  =(const float*)d_in[5];
  const float* mu1  =(const float*)d_in[6];
  const float* va1  =(const float*)d_in[7];
  const float* nw   =(const float*)d_in[8];
  const float* nb   =(const float*)d_in[9];
  const float* hw   =(const float*)d_in[10];
  const float* hb   =(const float*)d_in[11];
  const float* fw   =(const float*)d_in[12];
  const float* fb   =(const float*)d_in[13];
  const float* gf   =(const float*)d_in[14];
  const float* bef  =(const float*)d_in[15];
  const float* muf  =(const float*)d_in[16];
  const float* vaf  =(const float*)d_in[17];
  const float* rw   =(const float*)d_in[18];
  const float* rb   =(const float*)d_in[19];
  const float* gr   =(const float*)d_in[20];
  const float* ber  =(const float*)d_in[21];
  const float* mur  =(const float*)d_in[22];
  const float* var_ =(const float*)d_in[23];
  float* out=(float*)d_out;

  char* ws=(char*)d_ws;
  size_t o=0;
  auto alloc=[&](size_t bytes)->char*{ char* p=ws+o; o+=(bytes+255)&~(size_t)255; return p; };
  const size_t NN=(size_t)NP*NP;
  float* Wt    =(float*)alloc((size_t)BB*NP*ICH*4);   // 16.8 MB
  u16*   ndT   =(u16*)  alloc((size_t)BB*ICH*NP*2);   // 8.4 MB
  float* iw    =(float*)alloc(NN*4);                  // 67.1 MB
  u16*   b0    =(u16*)  alloc(NN*2);                  // 33.6 MB
  u16*   bh1   =(u16*)  alloc(NN*2);                  // 33.6 MB
  float* bh2   =(float*)alloc(NN*4);                  // 67.1 MB
  float* trawc =(float*)alloc((size_t)3*NP*ICH*4);    // 12.6 MB
  float* G     =(float*)alloc((size_t)3*ICH*ICH*4);
  float* Wcat  =(float*)alloc((size_t)CINCH*1024*4);
  float* evec  =(float*)alloc(CINCH*4);
  float* cf    =(float*)alloc(ICH*4);
  float* sf    =(float*)alloc(ICH*4);
  float* tf    =(float*)alloc(ICH*4);
  if(o > ws_size){
    k_diag<<<dim3((out_size+255)/256),dim3(256),0,stream>>>(out, out_size, (float)ws_size);
    return;
  }
  dim3 blk(256);
  k_prepA<<<dim3(769),blk,0,stream>>>(fw,hw,hb,fb,gf,bef,muf,vaf,G,cf,sf,tf);
  k_prepB<<<dim3(512),blk,0,stream>>>(rw,rb,G,cf,sf,tf,Wcat,evec);
  k_proj<<<dim3(NP/32,BB),blk,0,stream>>>(x,w1w,w1b,g1,be1,mu1,va1,nw,nb,Wt,ndT);
  for(int b=0;b<BB;b++){
    const float* Wt_b  = Wt + (size_t)b*NP*ICH;
    const u16*   ndT_b = ndT + (size_t)b*ICH*NP;
    const float* x_b   = x + (size_t)b*CINCH*NP;
    float*       out_b = out + (size_t)b*CINCH*NP;
    k_iw <<<dim3(2080),blk,0,stream>>>(Wt_b,iw);
    k_b0 <<<dim3(8192),blk,0,stream>>>(iw,b0,delta);
    k_nn0<<<dim3(528),blk,0,stream>>>(b0,bh1);
    k_nn1<<<dim3(528),blk,0,stream>>>(bh1,b0,bh2);
    k_pv3<<<dim3(256,3),blk,0,stream>>>(iw,bh1,bh2,ndT_b,delta,trawc);
    k_tail2<<<dim3(64,8),blk,0,stream>>>(trawc,Wcat,evec,x_b,gr,ber,mur,var_,out_b);
  }
}

// Round 4
// 4197.343 us; speedup vs baseline: 3.0474x; 1.4734x over previous
//
#include <hip/hip_runtime.h>

#define CINCH 512
#define ICH 256
#define NP 4096
#define BB 4

typedef __attribute__((ext_vector_type(8))) short bf16x8;
typedef __attribute__((ext_vector_type(8))) unsigned short u16x8;
typedef __attribute__((ext_vector_type(4))) float f32x4;
typedef __attribute__((ext_vector_type(4))) int i32x4;
typedef unsigned short u16;
typedef unsigned char u8;

__device__ __forceinline__ u16 f2bf(float f){
  unsigned u = __builtin_bit_cast(unsigned, f);
  u += 0x7FFFu + ((u>>16)&1u);
  return (u16)(u>>16);
}

__device__ __forceinline__ float b0_thr(float dv){
  if (dv <= 0.f) return -3.4e38f;
  if (dv >= 1.f) return  3.4e38f;
  return (float)log((double)dv/(1.0-(double)dv));
}

// ---------------- K1: wfeat (bn1, fp64 acc) + nodesT (bf16) ----------------
__global__ __launch_bounds__(256) void k_proj(const float* __restrict__ x,
    const float* __restrict__ w1w, const float* __restrict__ w1b,
    const float* __restrict__ g1, const float* __restrict__ be1,
    const float* __restrict__ mu1, const float* __restrict__ va1,
    const float* __restrict__ nw, const float* __restrict__ nb,
    float* __restrict__ Wt, u16* __restrict__ ndT){
  const int b = blockIdx.y;
  const int n0 = blockIdx.x*32;
  const int t = threadIdx.x;
  __shared__ float xs[32][33];
  double acc1[32];
  float  acc2[32];
  #pragma unroll
  for(int i=0;i<32;i++){acc1[i]=0.0;acc2[i]=0.f;}
  const float* xb = x + (size_t)b*CINCH*NP + n0;
  for(int cb=0; cb<CINCH; cb+=32){
    __syncthreads();
    {
      int cs=t>>3, nv=(t&7)*4;
      float4 v = *(const float4*)(xb + (size_t)(cb+cs)*NP + nv);
      xs[cs][nv]=v.x; xs[cs][nv+1]=v.y; xs[cs][nv+2]=v.z; xs[cs][nv+3]=v.w;
    }
    __syncthreads();
    const float* p1 = w1w + (size_t)t*CINCH + cb;
    const float* p2 = nw  + (size_t)t*CINCH + cb;
    #pragma unroll
    for(int i0=0;i0<32;i0+=8){
      float wr1[8], wr2[8];
      #pragma unroll
      for(int i=0;i<8;i+=4){
        float4 a=*(const float4*)(p1+i0+i); wr1[i]=a.x;wr1[i+1]=a.y;wr1[i+2]=a.z;wr1[i+3]=a.w;
        float4 c=*(const float4*)(p2+i0+i); wr2[i]=c.x;wr2[i+1]=c.y;wr2[i+2]=c.z;wr2[i+3]=c.w;
      }
      #pragma unroll
      for(int i=0;i<8;i++){
        float wa=wr1[i], wb=wr2[i];
        #pragma unroll
        for(int n=0;n<32;n++){
          float xv = xs[i0+i][n];
          acc1[n] += (double)wa*(double)xv;
          acc2[n] = fmaf(wb, xv, acc2[n]);
        }
      }
    }
  }
  float inv = g1[t]*rsqrtf(va1[t]+1e-5f);
  float add = be1[t]-mu1[t]*inv;
  float b1 = w1b[t], b2 = nb[t];
  u16 nb_[32];
  #pragma unroll
  for(int n=0;n<32;n++){
    Wt[((size_t)b*NP + n0+n)*ICH + t] = ((float)(acc1[n]+(double)b1))*inv + add;
    nb_[n] = f2bf(acc2[n]+b2);
  }
  u16* np_ = ndT + ((size_t)b*ICH + t)*NP + n0;
  #pragma unroll
  for(int q=0;q<8;q++) *(ushort4*)(np_ + q*4) = *(ushort4*)&nb_[q*4];
}

// ---------------- K2: iw = Wt Wt^T / 16 (fp64 acc) + b0 i8, symmetric ----------------
__global__ __launch_bounds__(256) void k_iw(const float* __restrict__ Wb,
    float* __restrict__ ob, char* __restrict__ b0, const float* __restrict__ delta){
  int tt = blockIdx.x;
  int bi = (int)((sqrtf(8.f*(float)tt+1.f)-1.f)*0.5f);
  while(bi*(bi+1)/2 > tt) bi--;
  while((bi+1)*(bi+2)/2 <= tt) bi++;
  int bj = tt - bi*(bi+1)/2;
  const int r0=bi*64, c0=bj*64;
  const float thr = b0_thr(delta[0]);
  __shared__ float as_[64][33], bs_[64][33];
  const int t=threadIdx.x, tx=t&15, ty=t>>4;
  double acc[4][4];
  #pragma unroll
  for(int i=0;i<4;i++)
    #pragma unroll
    for(int j=0;j<4;j++) acc[i][j]=0.0;
  for(int k0=0;k0<ICH;k0+=32){
    __syncthreads();
    {
      int r=t>>3, kv=(t&7)*4;
      #pragma unroll
      for(int rr=r; rr<64; rr+=32){
        float4 va=*(const float4*)(Wb + (size_t)(r0+rr)*ICH + k0+kv);
        as_[rr][kv]=va.x; as_[rr][kv+1]=va.y; as_[rr][kv+2]=va.z; as_[rr][kv+3]=va.w;
        float4 vb=*(const float4*)(Wb + (size_t)(c0+rr)*ICH + k0+kv);
        bs_[rr][kv]=vb.x; bs_[rr][kv+1]=vb.y; bs_[rr][kv+2]=vb.z; bs_[rr][kv+3]=vb.w;
      }
    }
    __syncthreads();
    #pragma unroll
    for(int k=0;k<32;k++){
      float av[4], bv[4];
      #pragma unroll
      for(int i=0;i<4;i++) av[i]=as_[ty*4+i][k];
      #pragma unroll
      for(int j=0;j<4;j++) bv[j]=bs_[tx*4+j][k];
      #pragma unroll
      for(int i=0;i<4;i++)
        #pragma unroll
        for(int j=0;j<4;j++)
          acc[i][j] += (double)av[i]*(double)bv[j];
    }
  }
  #pragma unroll
  for(int i=0;i<4;i++){
    #pragma unroll
    for(int j=0;j<4;j++){
      float v = (float)(acc[i][j]*0.0625);
      char bv = v>=thr ? 1 : 0;
      size_t rc=(size_t)(r0+ty*4+i)*NP + (c0+tx*4+j);
      ob[rc] = v; b0[rc] = bv;
      if(bi!=bj){
        size_t cr=(size_t)(c0+tx*4+j)*NP + (r0+ty*4+i);
        ob[cr] = v; b0[cr] = bv;
      }
    }
  }
}

// ---------------- K4: bh1 = b0 @ b0 via i8 MFMA (exact), split lo/hi i8 out ----------------
__global__ __launch_bounds__(256) void k_nn0(const char* __restrict__ b0,
    char* __restrict__ bh1lo, char* __restrict__ bh1hi){
  int tt = blockIdx.x;
  int bi = (int)((sqrtf(8.f*(float)tt+1.f)-1.f)*0.5f);
  while(bi*(bi+1)/2 > tt) bi--;
  while((bi+1)*(bi+2)/2 <= tt) bi++;
  int bj = tt - bi*(bi+1)/2;
  const int r0=bi*128, c0=bj*128;
  const int t=threadIdx.x, w=t>>6, l=t&63;
  const int wr=(w>>1)*64, wc=(w&1)*64, fr=l&15, fg=l>>4;
  const i32x4 zer={0,0,0,0};
  i32x4 acc[4][4];
  #pragma unroll
  for(int i=0;i<4;i++)
    #pragma unroll
    for(int j=0;j<4;j++) acc[i][j]=zer;
  for(int k0=0;k0<NP;k0+=64){
    const int kb = k0 + fg*16;
    i32x4 af[4], bf_[4];
    #pragma unroll
    for(int mi=0;mi<4;mi++) af[mi]=*(const i32x4*)(b0 + (size_t)(r0+wr+mi*16+fr)*NP + kb);
    #pragma unroll
    for(int nj=0;nj<4;nj++) bf_[nj]=*(const i32x4*)(b0 + (size_t)(c0+wc+nj*16+fr)*NP + kb);
    #pragma unroll
    for(int mi=0;mi<4;mi++)
      #pragma unroll
      for(int nj=0;nj<4;nj++)
        acc[mi][nj]=__builtin_amdgcn_mfma_i32_16x16x64_i8(af[mi],bf_[nj],acc[mi][nj],0,0,0);
  }
  #pragma unroll
  for(int mi=0;mi<4;mi++){
    #pragma unroll
    for(int nj=0;nj<4;nj++){
      int gr=r0+wr+mi*16+fg*4, gc=c0+wc+nj*16+fr;
      #pragma unroll
      for(int r=0;r<4;r++){
        int v=acc[mi][nj][r];
        char lo=(char)(v&127), hi=(char)(v>>7);
        size_t rc=(size_t)(gr+r)*NP+gc;
        bh1lo[rc]=lo; bh1hi[rc]=hi;
        if(bi!=bj){
          size_t cr=(size_t)gc*NP+(gr+r);
          bh1lo[cr]=lo; bh1hi[cr]=hi;
        }
      }
    }
  }
}

// ---------------- K5: bh2 = bh1 @ b0 (f32 out, exact, i8 MFMA lo/hi) ----------------
__global__ __launch_bounds__(256) void k_nn1(const char* __restrict__ bh1lo,
    const char* __restrict__ bh1hi, const char* __restrict__ b0,
    float* __restrict__ bh2){
  int tt = blockIdx.x;
  int bi = (int)((sqrtf(8.f*(float)tt+1.f)-1.f)*0.5f);
  while(bi*(bi+1)/2 > tt) bi--;
  while((bi+1)*(bi+2)/2 <= tt) bi++;
  int bj = tt - bi*(bi+1)/2;
  const int r0=bi*128, c0=bj*128;
  const int t=threadIdx.x, w=t>>6, l=t&63;
  const int wr=(w>>1)*64, wc=(w&1)*64, fr=l&15, fg=l>>4;
  const i32x4 zer={0,0,0,0};
  i32x4 accl[4][4], acch[4][4];
  #pragma unroll
  for(int i=0;i<4;i++)
    #pragma unroll
    for(int j=0;j<4;j++){accl[i][j]=zer; acch[i][j]=zer;}
  for(int k0=0;k0<NP;k0+=64){
    const int kb = k0 + fg*16;
    i32x4 al[4], ah[4], bf_[4];
    #pragma unroll
    for(int mi=0;mi<4;mi++){
      size_t ro=(size_t)(r0+wr+mi*16+fr)*NP + kb;
      al[mi]=*(const i32x4*)(bh1lo + ro);
      ah[mi]=*(const i32x4*)(bh1hi + ro);
    }
    #pragma unroll
    for(int nj=0;nj<4;nj++) bf_[nj]=*(const i32x4*)(b0 + (size_t)(c0+wc+nj*16+fr)*NP + kb);
    #pragma unroll
    for(int mi=0;mi<4;mi++)
      #pragma unroll
      for(int nj=0;nj<4;nj++){
        accl[mi][nj]=__builtin_amdgcn_mfma_i32_16x16x64_i8(al[mi],bf_[nj],accl[mi][nj],0,0,0);
        acch[mi][nj]=__builtin_amdgcn_mfma_i32_16x16x64_i8(ah[mi],bf_[nj],acch[mi][nj],0,0,0);
      }
  }
  #pragma unroll
  for(int mi=0;mi<4;mi++){
    #pragma unroll
    for(int nj=0;nj<4;nj++){
      int gr=r0+wr+mi*16+fg*4, gc=c0+wc+nj*16+fr;
      #pragma unroll
      for(int r=0;r<4;r++){
        float v = (float)(accl[mi][nj][r] + (acch[mi][nj][r]<<7));
        bh2[(size_t)(gr+r)*NP+gc]=v;
        if(bi!=bj) bh2[(size_t)gc*NP+(gr+r)]=v;
      }
    }
  }
}

// ---------------- K6: fused flash-style softmax @ nodes, 3 hops in one grid ----------------
template<int H>
__device__ __forceinline__ void pv_body(const float* __restrict__ iw,
    const u8* __restrict__ bh1lo, const u8* __restrict__ bh1hi,
    const float* __restrict__ bh2,
    const u16* __restrict__ ndT, const float* __restrict__ delta,
    float* __restrict__ traw){
  const int rs = blockIdx.x;                 // 16-row set
  const int t = threadIdx.x, w = t>>6, l = t&63, fr = l&15, fg = l>>4;
  const int row = rs*16 + fr;
  const int kbase = w*1024;                  // per-wave K quarter
  const float thr = b0_thr(delta[0]);
  const f32x4 zer={0.f,0.f,0.f,0.f};
  f32x4 acc[16];
  #pragma unroll
  for(int i=0;i<16;i++) acc[i]=zer;
  float m_run=-3.0e38f, s_run=0.f;
  const float* ip = iw    + (size_t)row*NP + kbase;
  const u8*   ulo = bh1lo + (size_t)row*NP + kbase;
  const u8*   uhi = bh1hi + (size_t)row*NP + kbase;
  const float* fp = bh2   + (size_t)row*NP + kbase;
  for(int k0=0;k0<1024;k0+=32){
    const int kb = k0 + fg*8;
    bf16x8 bfr[16];
    #pragma unroll
    for(int nj=0;nj<16;nj++)
      bfr[nj]=*(const bf16x8*)(ndT + (size_t)(nj*16+fr)*NP + kbase + kb);
    float vv[8];
    {
      float4 v0=*(const float4*)(ip+kb), v1=*(const float4*)(ip+kb+4);
      vv[0]=v0.x; vv[1]=v0.y; vv[2]=v0.z; vv[3]=v0.w;
      vv[4]=v1.x; vv[5]=v1.y; vv[6]=v1.z; vv[7]=v1.w;
    }
    float lg[8];
    if(H==0){
      #pragma unroll
      for(int e=0;e<8;e++) lg[e]=vv[e]>=thr?vv[e]:0.f;
    } else if(H==1){
      unsigned long long llo=*(const unsigned long long*)(ulo+kb);
      unsigned long long lhi=*(const unsigned long long*)(uhi+kb);
      #pragma unroll
      for(int e=0;e<8;e++){
        int bh = (int)((llo>>(8*e))&255u) | ((int)((lhi>>(8*e))&255u)<<7);
        lg[e]=(float)bh*vv[e];
      }
    } else {
      float4 h0=*(const float4*)(fp+kb), h1=*(const float4*)(fp+kb+4);
      lg[0]=h0.x*vv[0]; lg[1]=h0.y*vv[1]; lg[2]=h0.z*vv[2]; lg[3]=h0.w*vv[3];
      lg[4]=h1.x*vv[4]; lg[5]=h1.y*vv[5]; lg[6]=h1.z*vv[6]; lg[7]=h1.w*vv[7];
    }
    float m_t = fmaxf(fmaxf(fmaxf(lg[0],lg[1]),fmaxf(lg[2],lg[3])),
                      fmaxf(fmaxf(lg[4],lg[5]),fmaxf(lg[6],lg[7])));
    m_t = fmaxf(m_t, __shfl_xor(m_t,16));
    m_t = fmaxf(m_t, __shfl_xor(m_t,32));     // row max over this 32-k tile
    if(__any(m_t > m_run + 6.0f)){
      float m_new = fmaxf(m_run, m_t);
      float sc = __expf(m_run - m_new);
      s_run *= sc;
      #pragma unroll
      for(int r=0;r<4;r++){
        float scr = __shfl(sc, fg*4+r);
        #pragma unroll
        for(int nj=0;nj<16;nj++) acc[nj][r]*=scr;
      }
      m_run = m_new;
    }
    bf16x8 af; float ss=0.f;
    #pragma unroll
    for(int e=0;e<8;e++){
      float p=__expf(lg[e]-m_run); ss+=p;
      af[e]=(short)f2bf(p);
    }
    s_run += ss;
    #pragma unroll
    for(int nj=0;nj<16;nj++)
      acc[nj]=__builtin_amdgcn_mfma_f32_16x16x32_bf16(af,bfr[nj],acc[nj],0,0,0);
  }
  s_run += __shfl_xor(s_run,16);
  s_run += __shfl_xor(s_run,32);
  __shared__ float Lm[4][16], Ls[4][16];
  __shared__ float Lacc[2][16][4][64];
  if(fg==0) Lm[w][fr]=m_run;
  __syncthreads();
  float f_c[4];
  #pragma unroll
  for(int r=0;r<4;r++){
    int rr=fg*4+r;
    float ms=fmaxf(fmaxf(Lm[0][rr],Lm[1][rr]),fmaxf(Lm[2][rr],Lm[3][rr]));
    f_c[r]=__expf(Lm[w][rr]-ms);
  }
  {
    float ms=fmaxf(fmaxf(Lm[0][fr],Lm[1][fr]),fmaxf(Lm[2][fr],Lm[3][fr]));
    float fs=__expf(Lm[w][fr]-ms);
    if(fg==0) Ls[w][fr]=s_run*fs;
  }
  #pragma unroll
  for(int nj=0;nj<16;nj++)
    #pragma unroll
    for(int r=0;r<4;r++) acc[nj][r]*=f_c[r];
  if(w==1||w==3){
    int Ri=(w==1)?0:1;
    #pragma unroll
    for(int nj=0;nj<16;nj++)
      #pragma unroll
      for(int r=0;r<4;r++) Lacc[Ri][nj][r][l]=acc[nj][r];
  }
  __syncthreads();
  if(w==0||w==2){
    int Ri=(w==0)?0:1;
    #pragma unroll
    for(int nj=0;nj<16;nj++)
      #pragma unroll
      for(int r=0;r<4;r++) acc[nj][r]+=Lacc[Ri][nj][r][l];
  }
  __syncthreads();
  if(w==2){
    #pragma unroll
    for(int nj=0;nj<16;nj++)
      #pragma unroll
      for(int r=0;r<4;r++) Lacc[0][nj][r][l]=acc[nj][r];
  }
  __syncthreads();
  if(w==0){
    float sst[4];
    #pragma unroll
    for(int r=0;r<4;r++){
      int rr=fg*4+r;
      sst[r]=1.0f/(Ls[0][rr]+Ls[1][rr]+Ls[2][rr]+Ls[3][rr]);
    }
    #pragma unroll
    for(int nj=0;nj<16;nj++)
      #pragma unroll
      for(int r=0;r<4;r++){
        float v=(acc[nj][r]+Lacc[0][nj][r][l])*sst[r];
        traw[(size_t)(rs*16+fg*4+r)*ICH + nj*16+fr]=v;
      }
  }
}

__global__ __launch_bounds__(256) void k_pv3(const float* __restrict__ iw,
    const u8* __restrict__ bh1lo, const u8* __restrict__ bh1hi,
    const float* __restrict__ bh2,
    const u16* __restrict__ ndT, const float* __restrict__ delta,
    float* __restrict__ trawcat){
  float* traw = trawcat + (size_t)blockIdx.y*NP*ICH;
  if(blockIdx.y==0)      pv_body<0>(iw,bh1lo,bh1hi,bh2,ndT,delta,traw);
  else if(blockIdx.y==1) pv_body<1>(iw,bh1lo,bh1hi,bh2,ndT,delta,traw);
  else                   pv_body<2>(iw,bh1lo,bh1hi,bh2,ndT,delta,traw);
}

// ---------------- prep: fold hop/fuse/bnf into res GEMM ----------------
__global__ __launch_bounds__(256) void k_prepA(const float* __restrict__ fw,
    const float* __restrict__ hw, const float* __restrict__ hb,
    const float* __restrict__ fb,
    const float* __restrict__ gf, const float* __restrict__ bef,
    const float* __restrict__ muf, const float* __restrict__ vaf,
    float* __restrict__ G, float* __restrict__ cf,
    float* __restrict__ sf, float* __restrict__ tf){
  const int t=threadIdx.x;
  if(blockIdx.x<768){
    int i=blockIdx.x>>8, oc=blockIdx.x&255;
    float s=0.f;
    const float* fr_=fw + (size_t)oc*768 + i*256;
    const float* hp=hw + (size_t)i*ICH*ICH + t;
    for(int j=0;j<256;j++) s=fmaf(fr_[j], hp[(size_t)j*ICH], s);
    G[((size_t)i*ICH + oc)*ICH + t]=s;
  } else {
    float iv=gf[t]*rsqrtf(vaf[t]+1e-5f);
    sf[t]=iv;
    tf[t]=bef[t]-muf[t]*iv;
    float s=fb[t];
    const float* fr_=fw + (size_t)t*768;
    for(int k=0;k<768;k++) s=fmaf(fr_[k], hb[k], s);
    cf[t]=s;
  }
}

__global__ __launch_bounds__(256) void k_prepB(const float* __restrict__ rw,
    const float* __restrict__ rb, const float* __restrict__ G,
    const float* __restrict__ cf, const float* __restrict__ sf,
    const float* __restrict__ tf, float* __restrict__ Wcat,
    float* __restrict__ evec){
  const int oc=blockIdx.x, t=threadIdx.x;
  __shared__ float rs_[256], rw2_[256];
  rw2_[t]=rw[(size_t)oc*512 + 256 + t];
  rs_[t]=rw2_[t]*sf[t];
  __syncthreads();
  Wcat[(size_t)oc*1024 + t] = rw[(size_t)oc*512 + t];
  #pragma unroll
  for(int i=0;i<3;i++){
    float s=0.f;
    const float* gp=G + (size_t)i*ICH*ICH + t;
    for(int m=0;m<256;m++) s=fmaf(rs_[m], gp[(size_t)m*ICH], s);
    Wcat[(size_t)oc*1024 + 256 + i*256 + t]=s;
  }
  if(t==0){
    float s=rb[oc];
    for(int m=0;m<256;m++) s=fmaf(rs_[m],cf[m],s)+rw2_[m]*tf[m];
    evec[oc]=s;
  }
}

// ---------------- tail: out = bnr( R0@x256 + Wcat_hops@trawcat + e ) ----------------
__global__ __launch_bounds__(256) void k_tail2(const float* __restrict__ trawcat,
    const float* __restrict__ Wcat, const float* __restrict__ evec,
    const float* __restrict__ xsrc,
    const float* __restrict__ g, const float* __restrict__ be,
    const float* __restrict__ mu, const float* __restrict__ va,
    float* __restrict__ Cout){
  const int n0=blockIdx.x*64, c0=blockIdx.y*64;
  __shared__ float as_[64][33], bs_[64][33];
  const int t=threadIdx.x, tx=t&15, ty=t>>4;
  float acc[4][4];
  #pragma unroll
  for(int i=0;i<4;i++)
    #pragma unroll
    for(int j=0;j<4;j++) acc[i][j]=0.f;
  for(int k0=0;k0<1024;k0+=32){
    __syncthreads();
    if(k0<256){
      int k=t>>4, nv=(t&15)*4;
      #pragma unroll
      for(int kk=k;kk<32;kk+=16){
        float4 v=*(const float4*)(xsrc + (size_t)(k0+kk)*NP + n0+nv);
        as_[nv+0][kk]=v.x; as_[nv+1][kk]=v.y; as_[nv+2][kk]=v.z; as_[nv+3][kk]=v.w;
      }
    } else {
      int hop=(k0-256)>>8, kk0=(k0-256)&255;
      const float* A=trawcat + (size_t)hop*NP*ICH;
      int r=t>>3, kv=(t&7)*4;
      #pragma unroll
      for(int rr=r;rr<64;rr+=32){
        float4 v=*(const float4*)(A + (size_t)(n0+rr)*ICH + kk0+kv);
        as_[rr][kv]=v.x; as_[rr][kv+1]=v.y; as_[rr][kv+2]=v.z; as_[rr][kv+3]=v.w;
      }
    }
    {
      int r=t>>3, kv=(t&7)*4;
      #pragma unroll
      for(int rr=r;rr<64;rr+=32){
        float4 v=*(const float4*)(Wcat + (size_t)(c0+rr)*1024 + k0+kv);
        bs_[rr][kv]=v.x; bs_[rr][kv+1]=v.y; bs_[rr][kv+2]=v.z; bs_[rr][kv+3]=v.w;
      }
    }
    __syncthreads();
    #pragma unroll
    for(int k=0;k<32;k++){
      float av[4],bv[4];
      #pragma unroll
      for(int i=0;i<4;i++) av[i]=as_[ty*4+i][k];
      #pragma unroll
      for(int j=0;j<4;j++) bv[j]=bs_[tx*4+j][k];
      #pragma unroll
      for(int i=0;i<4;i++)
        #pragma unroll
        for(int j=0;j<4;j++) acc[i][j]+=av[i]*bv[j];
    }
  }
  const int col=c0+tx*4, row=n0+ty*4;
  float sc[4], ad[4];
  #pragma unroll
  for(int j=0;j<4;j++){
    int c=col+j;
    float iv=g[c]*rsqrtf(va[c]+1e-5f);
    sc[j]=iv; ad[j]=be[c]-mu[c]*iv + evec[c]*iv;
  }
  #pragma unroll
  for(int j=0;j<4;j++){
    float4 ov;
    ov.x=acc[0][j]*sc[j]+ad[j]; ov.y=acc[1][j]*sc[j]+ad[j];
    ov.z=acc[2][j]*sc[j]+ad[j]; ov.w=acc[3][j]*sc[j]+ad[j];
    *(float4*)(Cout + (size_t)(col+j)*NP + row) = ov;
  }
}

__global__ void k_diag(float* out, int n, float val){
  int i = blockIdx.x*256 + threadIdx.x;
  if(i<n) out[i] = (i==0)? val : 0.f;
}

extern "C" void kernel_launch(void* const* d_in, const int* in_sizes, int n_in,
                              void* d_out, int out_size, void* d_ws, size_t ws_size,
                              hipStream_t stream){
  const float* x    =(const float*)d_in[0];
  const float* delta=(const float*)d_in[1];
  const float* w1w  =(const float*)d_in[2];
  const float* w1b  =(const float*)d_in[3];
  const float* g1   =(const float*)d_in[4];
  const float* be1  =(const float*)d_in[5];
  const float* mu1  =(const float*)d_in[6];
  const float* va1  =(const float*)d_in[7];
  const float* nw   =(const float*)d_in[8];
  const float* nb   =(const float*)d_in[9];
  const float* hw   =(const float*)d_in[10];
  const float* hb   =(const float*)d_in[11];
  const float* fw   =(const float*)d_in[12];
  const float* fb   =(const float*)d_in[13];
  const float* gf   =(const float*)d_in[14];
  const float* bef  =(const float*)d_in[15];
  const float* muf  =(const float*)d_in[16];
  const float* vaf  =(const float*)d_in[17];
  const float* rw   =(const float*)d_in[18];
  const float* rb   =(const float*)d_in[19];
  const float* gr   =(const float*)d_in[20];
  const float* ber  =(const float*)d_in[21];
  const float* mur  =(const float*)d_in[22];
  const float* var_ =(const float*)d_in[23];
  float* out=(float*)d_out;

  char* ws=(char*)d_ws;
  size_t o=0;
  auto alloc=[&](size_t bytes)->char*{ char* p=ws+o; o+=(bytes+255)&~(size_t)255; return p; };
  const size_t NN=(size_t)NP*NP;
  float* Wt    =(float*)alloc((size_t)BB*NP*ICH*4);   // 16.8 MB
  u16*   ndT   =(u16*)  alloc((size_t)BB*ICH*NP*2);   // 8.4 MB
  float* iw    =(float*)alloc(NN*4);                  // 67.1 MB
  char*  b0    =       alloc(NN);                     // 16.8 MB
  char*  bh1lo =       alloc(NN);                     // 16.8 MB
  char*  bh1hi =       alloc(NN);                     // 16.8 MB
  float* bh2   =(float*)alloc(NN*4);                  // 67.1 MB
  float* trawc =(float*)alloc((size_t)3*NP*ICH*4);    // 12.6 MB
  float* G     =(float*)alloc((size_t)3*ICH*ICH*4);
  float* Wcat  =(float*)alloc((size_t)CINCH*1024*4);
  float* evec  =(float*)alloc(CINCH*4);
  float* cf    =(float*)alloc(ICH*4);
  float* sf    =(float*)alloc(ICH*4);
  float* tf    =(float*)alloc(ICH*4);
  if(o > ws_size){
    k_diag<<<dim3((out_size+255)/256),dim3(256),0,stream>>>(out, out_size, (float)ws_size);
    return;
  }
  dim3 blk(256);
  k_prepA<<<dim3(769),blk,0,stream>>>(fw,hw,hb,fb,gf,bef,muf,vaf,G,cf,sf,tf);
  k_prepB<<<dim3(512),blk,0,stream>>>(rw,rb,G,cf,sf,tf,Wcat,evec);
  k_proj<<<dim3(NP/32,BB),blk,0,stream>>>(x,w1w,w1b,g1,be1,mu1,va1,nw,nb,Wt,ndT);
  for(int b=0;b<BB;b++){
    const float* Wt_b  = Wt + (size_t)b*NP*ICH;
    const u16*   ndT_b = ndT + (size_t)b*ICH*NP;
    const float* x_b   = x + (size_t)b*CINCH*NP;
    float*       out_b = out + (size_t)b*CINCH*NP;
    k_iw <<<dim3(2080),blk,0,stream>>>(Wt_b,iw,b0,delta);
    k_nn0<<<dim3(528),blk,0,stream>>>(b0,bh1lo,bh1hi);
    k_nn1<<<dim3(528),blk,0,stream>>>(bh1lo,bh1hi,b0,bh2);
    k_pv3<<<dim3(256,3),blk,0,stream>>>(iw,(const u8*)bh1lo,(const u8*)bh1hi,bh2,ndT_b,delta,trawc);
    k_tail2<<<dim3(64,8),blk,0,stream>>>(trawc,Wcat,evec,x_b,gr,ber,mur,var_,out_b);
  }
}